// Round 7
// baseline (75.710 us; speedup 1.0000x reference)
//
#include <hip/hip_runtime.h>

typedef _Float16 f16x8  __attribute__((ext_vector_type(8)));
typedef _Float16 f16x4  __attribute__((ext_vector_type(4)));
typedef __fp16   hf2    __attribute__((ext_vector_type(2)));
typedef float    f32x4  __attribute__((ext_vector_type(4)));
typedef float    f32x16 __attribute__((ext_vector_type(16)));

namespace {
constexpr int kN = 4, kL = 1024, kS = 1024, kH = 16, kE = 64, kD = 64;
constexpr int kRowF = kH * kE;     // 1024 floats: s-row stride of K and V
constexpr int KVB = 128;           // keys per super-chunk (2 halves of 64)
constexpr int NCH = kS / KVB;      // 8 super-chunks
constexpr float SCL = 0.125f * 1.44269504088896340736f;  // 1/sqrt(E)*log2(e)
}

__device__ __forceinline__ unsigned pku(float a, float b) {
  union { hf2 h; unsigned u; } u;
  u.h = __builtin_amdgcn_cvt_pkrtz(a, b);
  return u.u;
}
__device__ __forceinline__ f16x4 pk4(float a, float b, float c, float d) {
  union { hf2 h2[2]; f16x4 v; } u;
  u.h2[0] = __builtin_amdgcn_cvt_pkrtz(a, b);
  u.h2[1] = __builtin_amdgcn_cvt_pkrtz(c, d);
  return u.v;
}

// Block = 4 waves x 32 q of one (n,h). K/V in LDS f16, super-chunks of 128
// keys = 2 independent 64-key halves sharing ONE barrier / stage / rescale.
// All per-half swizzle math identical to the verified round-5/6 layout.
// 32x32x16 MFMA; swapped scores S^T = K.Q^T (C/D: col=lane&31=q,
// row=(reg&3)+8*(reg>>2)+4*(lane>>5)=s); P -> PV B-frag via cvt_pkrtz +
// permlane32_swap. Staging: threads 0-127 stage half 0, 128-255 half 1.
__global__ __launch_bounds__(256, 2)
void attn_fwd_kernel(const float* __restrict__ Q, const float* __restrict__ K,
                     const float* __restrict__ V, const float* __restrict__ M,
                     const float* __restrict__ KLN, float* __restrict__ O)
{
  __shared__ _Float16 Ks[2][2][64 * 64];   // [buf][half][s*64 + swizzled e]
  __shared__ _Float16 Vt[2][2][64 * 64];   // [buf][half][d*64 + swizzled s]

  const int tid  = threadIdx.x;
  const int lane = tid & 63;
  const int wave = tid >> 6;       // 0..3
  const int l31  = lane & 31;      // q within wave-tile; s/d row in frags
  const int hi   = lane >> 5;
  const int shf  = tid >> 7;       // staging half (0..1)
  const int sr   = (tid >> 4) & 7; // staging row id within half
  const int sc4  = tid & 15;       // staging float4 column

  // XCD swizzle (512 % 8 == 0 -> bijective)
  const int swz = ((blockIdx.x & 7) << 6) | (blockIdx.x >> 3);
  const int nh = swz >> 3, qb = swz & 7;
  const int h = nh & (kH - 1), n = nh >> 4;
  const int qrow = qb * 128 + wave * 32 + l31;

  const float* Kp = K + ((size_t)n * kS * kH + h) * kE;
  const float* Vp = V + ((size_t)n * kS * kH + h) * kD;
  const float* Lp = KLN + (size_t)n * kS;
  const float* Mp = M + (size_t)qrow * kS;

  // ---- hoisted Q B-frags (pre-scaled): qf[ec], k = 16*ec + 8*hi + j ----
  f16x8 qf[4];
  {
    const float* Qp = Q + ((size_t)((size_t)n * kL + qrow) * kH + h) * kE;
    #pragma unroll
    for (int ec = 0; ec < 4; ++ec) {
      const f32x4 a = *reinterpret_cast<const f32x4*>(Qp + 16*ec + 8*hi);
      const f32x4 b = *reinterpret_cast<const f32x4*>(Qp + 16*ec + 8*hi + 4);
      union { f16x4 h4[2]; f16x8 v; } u;
      u.h4[0] = pk4(a[0]*SCL, a[1]*SCL, a[2]*SCL, a[3]*SCL);
      u.h4[1] = pk4(b[0]*SCL, b[1]*SCL, b[2]*SCL, b[3]*SCL);
      qf[ec] = u.v;
    }
  }

  // ---- per-thread LDS constants (identical to verified round-6 math) ----
  const int kxor = (l31 & 7) << 1;
  int keyv[2], vrowb[2];
  #pragma unroll
  for (int dt = 0; dt < 2; ++dt) {
    const int d = 32*dt + l31;
    keyv[dt] = ((4*((d>>2)&3) + (d&3)) ^ (d>>2)) & 15;
    vrowb[dt] = d * 64;
  }
  int hwv[4];
  #pragma unroll
  for (int jd = 0; jd < 4; ++jd)
    hwv[jd] = ((4*(sc4 & 3) + jd) ^ sc4) & 15;

  const f32x16 z16 = {0,0,0,0, 0,0,0,0, 0,0,0,0, 0,0,0,0};
  f32x16 acc[2] = {z16, z16};
  float mrun = -1e30f, lsum = 0.f;

  // ---- staging (each thread stages its half shf) ----
  f32x4 ka[8], va[8];
  auto load_kv = [&](int sbase) {
    const int hb = sbase + 64 * shf;
    #pragma unroll
    for (int i = 0; i < 8; ++i)
      ka[i] = *reinterpret_cast<const f32x4*>(Kp + (size_t)(hb + 8*i + sr) * kRowF + 4*sc4);
    #pragma unroll
    for (int qd = 0; qd < 2; ++qd)
      #pragma unroll
      for (int js = 0; js < 4; ++js)
        va[qd*4+js] = *reinterpret_cast<const f32x4*>(Vp + (size_t)(hb + 4*(sr+8*qd) + js) * kRowF + 4*sc4);
  };
  auto kv_write = [&](int buf) {
    #pragma unroll
    for (int i = 0; i < 8; ++i) {
      const int s = 8*i + sr;
      *reinterpret_cast<f16x4*>(&Ks[buf][shf][s*64 + ((sc4 ^ ((s & 7) << 1)) << 2)]) =
          pk4(ka[i][0], ka[i][1], ka[i][2], ka[i][3]);
    }
    #pragma unroll
    for (int qd = 0; qd < 2; ++qd)
      #pragma unroll
      for (int jd = 0; jd < 4; ++jd) {
        const int d = 4*sc4 + jd;
        const int slot = (sr + 8*qd) ^ hwv[jd];
        *reinterpret_cast<f16x4*>(&Vt[buf][shf][d*64 + slot*4]) =
            pk4(va[qd*4+0][jd], va[qd*4+1][jd], va[qd*4+2][jd], va[qd*4+3][jd]);
      }
  };

  // ---- prologue ----
  load_kv(0);
  kv_write(0);
  load_kv(KVB);

  for (int c = 0; c < NCH; ++c) {
    const int cur = c & 1;
    const int s0 = c * KVB;
    __syncthreads();
    if (c + 1 < NCH) kv_write(cur ^ 1);

    // ---- QK^T: all 4 s-tiles (2 halves x 2 subtiles), 16 MFMAs ----
    f32x16 xs[2][2];
    #pragma unroll
    for (int H = 0; H < 2; ++H)
      #pragma unroll
      for (int st = 0; st < 2; ++st) {
        f32x16 cc = z16;
        __builtin_amdgcn_s_setprio(1);
        #pragma unroll
        for (int ec = 0; ec < 4; ++ec) {
          const f16x8 kf = *reinterpret_cast<const f16x8*>(
              &Ks[cur][H][l31*64 + st*2048 + ((((ec << 2) + (hi << 1)) ^ kxor) << 2)]);
          cc = __builtin_amdgcn_mfma_f32_32x32x16_f16(kf, qf[ec], cc, 0, 0, 0);
        }
        __builtin_amdgcn_s_setprio(0);
        xs[H][st] = cc;
      }

    if (c + 2 < NCH) load_kv((c + 2) * KVB);   // consumed top of body c+1

    // ---- logits ----
    #pragma unroll
    for (int H = 0; H < 2; ++H)
      #pragma unroll
      for (int st = 0; st < 2; ++st) {
        const int sb = s0 + 64*H + 32*st;
        #pragma unroll
        for (int m = 0; m < 4; ++m) {
          const f32x4 mv = *reinterpret_cast<const f32x4*>(Mp + sb + 8*m + 4*hi);
          const f32x4 lv = *reinterpret_cast<const f32x4*>(Lp + sb + 8*m + 4*hi);
          #pragma unroll
          for (int r = 0; r < 4; ++r)
            xs[H][st][4*m+r] = fmaf(mv[r] + lv[r], SCL, xs[H][st][4*m+r]);
        }
      }

    // ---- merged online softmax over 128 keys: tree max ----
    float mx[16];
    #pragma unroll
    for (int i = 0; i < 16; ++i)
      mx[i] = fmaxf(fmaxf(xs[0][0][i], xs[0][1][i]), fmaxf(xs[1][0][i], xs[1][1][i]));
    #pragma unroll
    for (int w = 8; w >= 1; w >>= 1)
      #pragma unroll
      for (int i = 0; i < w; ++i) mx[i] = fmaxf(mx[i], mx[i+w]);
    const float tmax = fmaxf(mx[0], __shfl_xor(mx[0], 32));

    if (!__all(tmax <= mrun + 8.f)) {          // defer-max THR=8 (log2)
      const float mnew = fmaxf(mrun, tmax);
      const float rs = __builtin_amdgcn_exp2f(mrun - mnew);
      mrun = mnew; lsum *= rs;
      acc[0] *= rs; acc[1] *= rs;
    }

    // ---- exp2 + tree sum ----
    #pragma unroll
    for (int H = 0; H < 2; ++H)
      #pragma unroll
      for (int st = 0; st < 2; ++st)
        #pragma unroll
        for (int i = 0; i < 16; ++i)
          xs[H][st][i] = __builtin_amdgcn_exp2f(xs[H][st][i] - mrun);
    float sm[16];
    #pragma unroll
    for (int i = 0; i < 16; ++i)
      sm[i] = (xs[0][0][i] + xs[0][1][i]) + (xs[1][0][i] + xs[1][1][i]);
    #pragma unroll
    for (int w = 8; w >= 1; w >>= 1)
      #pragma unroll
      for (int i = 0; i < w; ++i) sm[i] += sm[i+w];
    lsum += sm[0];                             // cross-lane sum in epilogue

    // ---- P -> PV B-frags via cvt_pk + permlane32_swap ----
    f16x8 pf[2][4];
    #pragma unroll
    for (int H = 0; H < 2; ++H)
      #pragma unroll
      for (int sc = 0; sc < 4; ++sc) {
        const int st = sc >> 1, b = (sc & 1) * 8;
        const unsigned k0 = pku(xs[H][st][b+0], xs[H][st][b+1]);
        const unsigned k1 = pku(xs[H][st][b+2], xs[H][st][b+3]);
        const unsigned s0_ = pku(xs[H][st][b+4], xs[H][st][b+5]);
        const unsigned s1_ = pku(xs[H][st][b+6], xs[H][st][b+7]);
        auto X = __builtin_amdgcn_permlane32_swap(k0, s0_, false, false);
        auto Y = __builtin_amdgcn_permlane32_swap(k1, s1_, false, false);
        union { unsigned u[4]; f16x8 v; } pu;
        pu.u[0] = X[0]; pu.u[1] = Y[0]; pu.u[2] = X[1]; pu.u[3] = Y[1];
        pf[H][sc] = pu.v;
      }

    // ---- PV: 16 MFMAs (2 halves x 2 d-tiles x 4 k-chunks) ----
    #pragma unroll
    for (int H = 0; H < 2; ++H)
      #pragma unroll
      for (int dt = 0; dt < 2; ++dt) {
        __builtin_amdgcn_s_setprio(1);
        #pragma unroll
        for (int sc = 0; sc < 4; ++sc) {
          const int sl0 = ((sc << 2) + (hi << 1)) ^ keyv[dt];
          union { f16x4 h4[2]; f16x8 v; } vu;
          vu.h4[0] = *reinterpret_cast<const f16x4*>(&Vt[cur][H][vrowb[dt] + (sl0 << 2)]);
          vu.h4[1] = *reinterpret_cast<const f16x4*>(&Vt[cur][H][vrowb[dt] + ((sl0 ^ 1) << 2)]);
          acc[dt] = __builtin_amdgcn_mfma_f32_32x32x16_f16(vu.v, pf[H][sc], acc[dt], 0, 0, 0);
        }
        __builtin_amdgcn_s_setprio(0);
      }
  }

  // ---- epilogue ----
  lsum += __shfl_xor(lsum, 32);
  const float inv = 1.f / lsum;
  float* Op = O + ((size_t)((size_t)n * kL + qrow) * kH + h) * kD;
  #pragma unroll
  for (int dt = 0; dt < 2; ++dt)
    #pragma unroll
    for (int m = 0; m < 4; ++m) {
      f32x4 o;
      o[0] = acc[dt][4*m+0] * inv;
      o[1] = acc[dt][4*m+1] * inv;
      o[2] = acc[dt][4*m+2] * inv;
      o[3] = acc[dt][4*m+3] * inv;
      *reinterpret_cast<f32x4*>(Op + 32*dt + 8*m + 4*hi) = o;
    }
}

extern "C" void kernel_launch(void* const* d_in, const int* in_sizes, int n_in,
                              void* d_out, int out_size, void* d_ws, size_t ws_size,
                              hipStream_t stream) {
  const float* Q   = (const float*)d_in[0];
  const float* K   = (const float*)d_in[1];
  const float* V   = (const float*)d_in[2];
  const float* M   = (const float*)d_in[3];
  const float* KLN = (const float*)d_in[4];
  float* O = (float*)d_out;

  dim3 grid(kN * kH * (kL / 128));  // 512 blocks
  dim3 block(256);                  // 4 waves, 32 queries each
  attn_fwd_kernel<<<grid, block, 0, stream>>>(Q, K, V, M, KLN, O);
}